// Round 5
// baseline (468.217 us; speedup 1.0000x reference)
//
#include <hip/hip_runtime.h>
#include <hip/hip_bf16.h>
#include <cstdint>

#define NB   2
#define NC   256
#define NSP  32768     // D*H*W
#define NG   32
#define CPG  8         // NC/NG
#define NH   8
#define HDIM 32
#define O3   768
#define NCH  64        // k_kv spatial chunks
#define GN_EPS 1e-5f

typedef __attribute__((ext_vector_type(4))) float f32x4;
typedef __attribute__((ext_vector_type(8))) short short8;
typedef __attribute__((ext_vector_type(4))) short s16x4;

static __device__ __forceinline__ float bf2f(unsigned short u) {
    union { unsigned int i; float f; } v; v.i = ((unsigned int)u) << 16; return v.f;
}
static __device__ __forceinline__ unsigned short f2bf(float f) {
    union { float f; unsigned int i; } v; v.f = f;
    unsigned int lsb = (v.i >> 16) & 1u;
    return (unsigned short)((v.i + 0x7fffu + lsb) >> 16);
}
static __device__ __forceinline__ float elu1(float x) {
    return x > 0.f ? x + 1.f : __expf(x);
}

// ---------------- weight fp32 -> bf16 ----------------
__global__ __launch_bounds__(256) void k_convw(const float* __restrict__ qkvw,
                                               const float* __restrict__ outw,
                                               unsigned short* __restrict__ w16,
                                               unsigned short* __restrict__ ow16) {
    int i = blockIdx.x * 256 + threadIdx.x;
    for (int idx = i; idx < O3 * NC; idx += gridDim.x * 256) w16[idx] = f2bf(qkvw[idx]);
    for (int idx = i; idx < NC * NC; idx += gridDim.x * 256) ow16[idx] = f2bf(outw[idx]);
}

// ---------------- per-(b,c) sum/sumsq, fp32 input ----------------
__global__ __launch_bounds__(256) void k_stat_f32(const float* __restrict__ x, float* __restrict__ part) {
    int bc = blockIdx.x;
    const float* p = x + (size_t)bc * NSP;
    int t = threadIdx.x;
    float s = 0.f, s2 = 0.f;
    for (int i = t * 4; i < NSP; i += 256 * 4) {
        float4 v = *reinterpret_cast<const float4*>(p + i);
        s  += v.x + v.y + v.z + v.w;
        s2 += v.x * v.x + v.y * v.y + v.z * v.z + v.w * v.w;
    }
    #pragma unroll
    for (int o = 32; o > 0; o >>= 1) { s += __shfl_down(s, o, 64); s2 += __shfl_down(s2, o, 64); }
    __shared__ float red[8];
    if ((t & 63) == 0) { red[(t >> 6) * 2] = s; red[(t >> 6) * 2 + 1] = s2; }
    __syncthreads();
    if (t == 0) {
        part[bc * 2]     = red[0] + red[2] + red[4] + red[6];
        part[bc * 2 + 1] = red[1] + red[3] + red[5] + red[7];
    }
}

// ---------------- finalize group stats: per (b,g) mu, rsig ----------------
__global__ __launch_bounds__(64) void k_gnfin(const float* __restrict__ part, float* __restrict__ stat) {
    int i = threadIdx.x;
    if (i < NB * NG) {
        int b = i / NG, g = i % NG;
        float s = 0.f, s2 = 0.f;
        #pragma unroll
        for (int cc = 0; cc < CPG; ++cc) {
            int bc = b * NC + g * CPG + cc;
            s += part[bc * 2]; s2 += part[bc * 2 + 1];
        }
        float cnt = (float)(CPG * NSP);
        float mu = s / cnt;
        float var = s2 / cnt - mu * mu;
        stat[i * 2] = mu;
        stat[i * 2 + 1] = rsqrtf(var + GN_EPS);
    }
}

// ---------------- fused gn1-apply + qkv GEMM + bias + elu + qsum, store q/k/v bf16 ----------------
// grid (NSP/64, NB), 256 threads (4 waves). A (weights) register-pipelined from L2, one kc ahead.
// No barriers in the K loop; only one __syncthreads after Ht staging.
__global__ __launch_bounds__(256, 3) void k_qkv(const float* __restrict__ x,
                                             const float* __restrict__ nw, const float* __restrict__ nb,
                                             const unsigned short* __restrict__ w16,
                                             const float* __restrict__ qkvb,
                                             const float* __restrict__ gn1,
                                             unsigned short* __restrict__ qb,
                                             unsigned short* __restrict__ kb,
                                             unsigned short* __restrict__ vb,
                                             float* __restrict__ qsb) {
    __shared__ unsigned short Ht[64][266];   // h transposed [n][c]; odd dword stride -> ~conflict-free
    int b = blockIdx.y;
    int n0 = blockIdx.x * 64;
    int t = threadIdx.x;

    {   // stage h = (x-mu)*rsig*nw + nb, transposed, bf16
        int n = t & 63, cq = t >> 6;
        const float* xcol = x + (size_t)b * NC * NSP + n0 + n;
        #pragma unroll 8
        for (int pass = 0; pass < 16; ++pass) {
            int c0 = pass * 16 + cq * 4;
            s16x4 pk;
            #pragma unroll
            for (int i = 0; i < 4; ++i) {
                int c = c0 + i;
                float xv = xcol[(size_t)c * NSP];
                int g = c >> 3;
                float mu = gn1[(b * NG + g) * 2], rs = gn1[(b * NG + g) * 2 + 1];
                float sc = rs * nw[c];
                float bi = nb[c] - mu * sc;
                pk[i] = (short)f2bf(xv * sc + bi);
            }
            *reinterpret_cast<s16x4*>(&Ht[n][c0]) = pk;
        }
    }
    __syncthreads();

    int w = t >> 6, l = t & 63, mr = l & 15, kg = l >> 4;
    for (int mp = 0; mp < 3; ++mp) {
        const unsigned short* arow[4];
        #pragma unroll
        for (int mt = 0; mt < 4; ++mt)
            arow[mt] = w16 + (size_t)(mp * 256 + w * 64 + mt * 16 + mr) * NC + kg * 8;
        f32x4 acc[4][4];
        #pragma unroll
        for (int a = 0; a < 4; ++a)
            #pragma unroll
            for (int n2 = 0; n2 < 4; ++n2) acc[a][n2] = (f32x4){0.f, 0.f, 0.f, 0.f};
        short8 afc[4], afn[4];
        #pragma unroll
        for (int mt = 0; mt < 4; ++mt) afc[mt] = *reinterpret_cast<const short8*>(arow[mt]);
        #pragma unroll 2
        for (int kc = 0; kc < 8; ++kc) {
            if (kc < 7) {
                #pragma unroll
                for (int mt = 0; mt < 4; ++mt)
                    afn[mt] = *reinterpret_cast<const short8*>(arow[mt] + (kc + 1) * 32);
            }
            int k0 = kc * 32 + kg * 8;
            short8 bfr[4];
            #pragma unroll
            for (int nt = 0; nt < 4; ++nt)
                bfr[nt] = *reinterpret_cast<const short8*>(&Ht[nt * 16 + mr][k0]);
            #pragma unroll
            for (int mt = 0; mt < 4; ++mt)
                #pragma unroll
                for (int nt = 0; nt < 4; ++nt)
                    acc[mt][nt] = __builtin_amdgcn_mfma_f32_16x16x32_bf16(afc[mt], bfr[nt], acc[mt][nt], 0, 0, 0);
            #pragma unroll
            for (int mt = 0; mt < 4; ++mt) afc[mt] = afn[mt];
        }
        unsigned short* dst = (mp == 0) ? qb : (mp == 1) ? kb : vb;
        #pragma unroll
        for (int nt = 0; nt < 4; ++nt) {
            int n = n0 + nt * 16 + mr;
            float sh0 = 0.f, sh1 = 0.f;
            #pragma unroll
            for (int mt = 0; mt < 4; ++mt)
                #pragma unroll
                for (int r = 0; r < 4; ++r) {
                    int olocal = w * 64 + mt * 16 + kg * 4 + r;
                    float val = acc[mt][nt][r] + qkvb[mp * 256 + olocal];
                    if (mp < 2) val = elu1(val);
                    dst[((size_t)(b * NC + olocal)) * NSP + n] = f2bf(val);
                    if (mt < 2) sh0 += val; else sh1 += val;
                }
            if (mp == 0) {   // qs[h][n] = sum_d q: reduce over kg lanes (xor 16,32)
                sh0 += __shfl_xor(sh0, 16, 64); sh0 += __shfl_xor(sh0, 32, 64);
                sh1 += __shfl_xor(sh1, 16, 64); sh1 += __shfl_xor(sh1, 32, 64);
                if (kg == 0) {
                    qsb[((size_t)(b * NH + w * 2)) * NSP + n]     = sh0;
                    qsb[((size_t)(b * NH + w * 2 + 1)) * NSP + n] = sh1;
                }
            }
        }
    }
}

// ---------------- KV partials via MFMA: KV[d][e] = sum_n k[d][n] v[e][n] ----------------
// grid (NCH, NH, NB), 256 threads (4 waves). Per block: 512 n, per wave 128 n.
__global__ __launch_bounds__(256) void k_kv(const unsigned short* __restrict__ kb,
                                            const unsigned short* __restrict__ vb,
                                            float* __restrict__ KVpart, float* __restrict__ Spart) {
    int ch = blockIdx.x, h = blockIdx.y, b = blockIdx.z;
    int t = threadIdx.x, w = t >> 6, l = t & 63;
    int d16 = l & 15, kg = l >> 4;
    size_t base = ((size_t)(b * NC + h * HDIM)) * NSP + ch * 512 + w * 128;
    const unsigned short* kp = kb + base;
    const unsigned short* vp = vb + base;

    f32x4 acc[2][2];
    #pragma unroll
    for (int a = 0; a < 2; ++a)
        #pragma unroll
        for (int c = 0; c < 2; ++c) acc[a][c] = (f32x4){0.f, 0.f, 0.f, 0.f};
    float s0 = 0.f, s1 = 0.f;
    #pragma unroll
    for (int step = 0; step < 4; ++step) {
        int nof = step * 32 + kg * 8;
        short8 ak0 = *reinterpret_cast<const short8*>(kp + (size_t)(d16) * NSP + nof);
        short8 ak1 = *reinterpret_cast<const short8*>(kp + (size_t)(16 + d16) * NSP + nof);
        short8 av0 = *reinterpret_cast<const short8*>(vp + (size_t)(d16) * NSP + nof);
        short8 av1 = *reinterpret_cast<const short8*>(vp + (size_t)(16 + d16) * NSP + nof);
        acc[0][0] = __builtin_amdgcn_mfma_f32_16x16x32_bf16(ak0, av0, acc[0][0], 0, 0, 0);
        acc[0][1] = __builtin_amdgcn_mfma_f32_16x16x32_bf16(ak0, av1, acc[0][1], 0, 0, 0);
        acc[1][0] = __builtin_amdgcn_mfma_f32_16x16x32_bf16(ak1, av0, acc[1][0], 0, 0, 0);
        acc[1][1] = __builtin_amdgcn_mfma_f32_16x16x32_bf16(ak1, av1, acc[1][1], 0, 0, 0);
        #pragma unroll
        for (int j = 0; j < 8; ++j) { s0 += bf2f((unsigned short)ak0[j]); s1 += bf2f((unsigned short)ak1[j]); }
    }
    s0 += __shfl_down(s0, 32, 64); s0 += __shfl_down(s0, 16, 64);
    s1 += __shfl_down(s1, 32, 64); s1 += __shfl_down(s1, 16, 64);

    __shared__ float red[4][1024];
    __shared__ float sred[4][32];
    #pragma unroll
    for (int et = 0; et < 2; ++et)
        #pragma unroll
        for (int nt = 0; nt < 2; ++nt)
            #pragma unroll
            for (int r = 0; r < 4; ++r) {
                int d = et * 16 + kg * 4 + r;
                int e = nt * 16 + d16;
                red[w][d * 32 + e] = acc[et][nt][r];
            }
    if (l < 16) { sred[w][l] = s0; sred[w][16 + l] = s1; }
    __syncthreads();
    int bh = b * NH + h;
    float* kvout = KVpart + ((size_t)bh * NCH + ch) * 1024;
    for (int i = t; i < 1024; i += 256) kvout[i] = red[0][i] + red[1][i] + red[2][i] + red[3][i];
    if (t < 32) Spart[(bh * NCH + ch) * 32 + t] = sred[0][t] + sred[1][t] + sred[2][t] + sred[3][t];
}

// ---------------- reduce partials: KV2f[d][e] = KV[d][e]/max(S[d],1e-6), fp32 ----------------
__global__ __launch_bounds__(256) void k_kvfin(const float* __restrict__ KVpart, const float* __restrict__ Spart,
                                               float* __restrict__ KV2f) {
    int bh = blockIdx.x, t = threadIdx.x;
    __shared__ float Sl[32];
    if (t < 32) {
        float s = 0.f;
        for (int ch = 0; ch < NCH; ++ch) s += Spart[(bh * NCH + ch) * 32 + t];
        Sl[t] = fmaxf(s, 1e-6f);
    }
    __syncthreads();
    for (int i = t; i < 1024; i += 256) {
        float s = 0.f;
        #pragma unroll 8
        for (int ch = 0; ch < NCH; ++ch) s += KVpart[((size_t)bh * NCH + ch) * 1024 + i];
        KV2f[bh * 1024 + i] = s / Sl[i >> 5];
    }
}

// ---------------- fold: Mf[b][o][h*32+d] = sum_e ow[o][h*32+e] * KV2f[b][h][d][e] ----------------
// grid (NH, NB), 256 threads (thread = o).
__global__ __launch_bounds__(256) void k_fold(const unsigned short* __restrict__ ow16,
                                              const float* __restrict__ KV2f,
                                              unsigned short* __restrict__ Mf) {
    int h = blockIdx.x, b = blockIdx.y, t = threadIdx.x;
    __shared__ float kv[HDIM][HDIM];
    for (int i = t; i < HDIM * HDIM; i += 256) kv[i >> 5][i & 31] = KV2f[(b * NH + h) * 1024 + i];
    __syncthreads();
    int o = t;
    float owv[32];
    #pragma unroll
    for (int e = 0; e < 32; ++e) owv[e] = bf2f(ow16[o * NC + h * 32 + e]);
    #pragma unroll
    for (int dq = 0; dq < 4; ++dq) {
        short8 pk;
        #pragma unroll
        for (int dr = 0; dr < 8; ++dr) {
            int d = dq * 8 + dr;
            float s = 0.f;
            #pragma unroll
            for (int e = 0; e < 32; ++e) s += owv[e] * kv[d][e];
            pk[dr] = (short)f2bf(s);
        }
        *reinterpret_cast<short8*>(Mf + ((size_t)b * NC + o) * NC + h * 32 + dq * 8) = pk;
    }
}

// ---------------- out GEMM: y[o][n] = sum_c Mf[o][c] * (q[c][n]/qs[h(c)][n]) + outb[o] ----------------
// grid (NSP/64, NB), 256 threads (4 waves). Same register-pipelined structure as k_qkv. Fused gn2 stats.
__global__ __launch_bounds__(256, 3) void k_out(const unsigned short* __restrict__ qb,
                                             const float* __restrict__ qsb,
                                             const unsigned short* __restrict__ Mf,
                                             const float* __restrict__ outb,
                                             unsigned short* __restrict__ yb,
                                             float* __restrict__ gn2part) {
    __shared__ unsigned short qT[64][266];
    int b = blockIdx.y, n0 = blockIdx.x * 64, t = threadIdx.x;

    {   // stage q' = q * (1/qs) transposed
        int n = t & 63, cq = t >> 6;
        const unsigned short* qcol = qb + (size_t)b * NC * NSP + n0 + n;
        #pragma unroll
        for (int h = 0; h < 8; ++h) {
            float rqh = 1.0f / fmaxf(qsb[((size_t)(b * NH + h)) * NSP + n0 + n], 1e-6f);
            #pragma unroll
            for (int p2 = 0; p2 < 2; ++p2) {
                int c0 = h * 32 + p2 * 16 + cq * 4;
                s16x4 pk;
                #pragma unroll
                for (int i = 0; i < 4; ++i)
                    pk[i] = (short)f2bf(bf2f(qcol[(size_t)(c0 + i) * NSP]) * rqh);
                *reinterpret_cast<s16x4*>(&qT[n][c0]) = pk;
            }
        }
    }
    __syncthreads();

    int w = t >> 6, l = t & 63, mr = l & 15, kg = l >> 4;
    const unsigned short* arow[4];
    #pragma unroll
    for (int mt = 0; mt < 4; ++mt)
        arow[mt] = Mf + (size_t)b * NC * NC + (size_t)(w * 64 + mt * 16 + mr) * NC + kg * 8;
    f32x4 acc[4][4];
    #pragma unroll
    for (int a = 0; a < 4; ++a)
        #pragma unroll
        for (int n2 = 0; n2 < 4; ++n2) acc[a][n2] = (f32x4){0.f, 0.f, 0.f, 0.f};
    short8 afc[4], afn[4];
    #pragma unroll
    for (int mt = 0; mt < 4; ++mt) afc[mt] = *reinterpret_cast<const short8*>(arow[mt]);
    #pragma unroll 2
    for (int kc = 0; kc < 8; ++kc) {
        if (kc < 7) {
            #pragma unroll
            for (int mt = 0; mt < 4; ++mt)
                afn[mt] = *reinterpret_cast<const short8*>(arow[mt] + (kc + 1) * 32);
        }
        int k0 = kc * 32 + kg * 8;
        short8 bfr[4];
        #pragma unroll
        for (int nt = 0; nt < 4; ++nt)
            bfr[nt] = *reinterpret_cast<const short8*>(&qT[nt * 16 + mr][k0]);
        #pragma unroll
        for (int mt = 0; mt < 4; ++mt)
            #pragma unroll
            for (int nt = 0; nt < 4; ++nt)
                acc[mt][nt] = __builtin_amdgcn_mfma_f32_16x16x32_bf16(afc[mt], bfr[nt], acc[mt][nt], 0, 0, 0);
        #pragma unroll
        for (int mt = 0; mt < 4; ++mt) afc[mt] = afn[mt];
    }
    // epilogue: store y, accumulate gn2 stats (sum, sumsq) per channel
    float s1[16], s2[16];
    #pragma unroll
    for (int i = 0; i < 16; ++i) { s1[i] = 0.f; s2[i] = 0.f; }
    #pragma unroll
    for (int mt = 0; mt < 4; ++mt) {
        #pragma unroll
        for (int nt = 0; nt < 4; ++nt) {
            int n = n0 + nt * 16 + mr;
            #pragma unroll
            for (int r = 0; r < 4; ++r) {
                int o = w * 64 + mt * 16 + kg * 4 + r;
                float val = acc[mt][nt][r] + outb[o];
                yb[((size_t)(b * NC + o)) * NSP + n] = f2bf(val);
                s1[mt * 4 + r] += val;
                s2[mt * 4 + r] += val * val;
            }
        }
    }
    #pragma unroll
    for (int i = 0; i < 16; ++i) {
        float a = s1[i], q2 = s2[i];
        a += __shfl_down(a, 8, 64);  q2 += __shfl_down(q2, 8, 64);
        a += __shfl_down(a, 4, 64);  q2 += __shfl_down(q2, 4, 64);
        a += __shfl_down(a, 2, 64);  q2 += __shfl_down(q2, 2, 64);
        a += __shfl_down(a, 1, 64);  q2 += __shfl_down(q2, 1, 64);
        if (mr == 0) {
            int o = w * 64 + (i >> 2) * 16 + kg * 4 + (i & 3);
            atomicAdd(&gn2part[(b * NC + o) * 2], a);
            atomicAdd(&gn2part[(b * NC + o) * 2 + 1], q2);
        }
    }
}

// ---------------- final: out = x + gn2(y) ----------------
__global__ __launch_bounds__(256) void k_final(const float* __restrict__ x,
                                               const unsigned short* __restrict__ yb,
                                               const float* __restrict__ onw, const float* __restrict__ onb,
                                               const float* __restrict__ gn2, float* __restrict__ out) {
    size_t base = ((size_t)blockIdx.x * 256 + threadIdx.x) * 8;
    int bc = (int)(base >> 15);           // b*NC + c
    int c = bc & (NC - 1);
    int b = bc >> 8;
    int g = c >> 3;
    float mu = gn2[(b * NG + g) * 2], rs = gn2[(b * NG + g) * 2 + 1];
    float sc = rs * onw[c], bi = onb[c] - mu * sc;
    short8 v = *reinterpret_cast<const short8*>(yb + base);
    float4 x0 = *reinterpret_cast<const float4*>(x + base);
    float4 x1 = *reinterpret_cast<const float4*>(x + base + 4);
    float4 o0, o1;
    o0.x = x0.x + bf2f((unsigned short)v[0]) * sc + bi;
    o0.y = x0.y + bf2f((unsigned short)v[1]) * sc + bi;
    o0.z = x0.z + bf2f((unsigned short)v[2]) * sc + bi;
    o0.w = x0.w + bf2f((unsigned short)v[3]) * sc + bi;
    o1.x = x1.x + bf2f((unsigned short)v[4]) * sc + bi;
    o1.y = x1.y + bf2f((unsigned short)v[5]) * sc + bi;
    o1.z = x1.z + bf2f((unsigned short)v[6]) * sc + bi;
    o1.w = x1.w + bf2f((unsigned short)v[7]) * sc + bi;
    *reinterpret_cast<float4*>(out + base) = o0;
    *reinterpret_cast<float4*>(out + base + 4) = o1;
}

extern "C" void kernel_launch(void* const* d_in, const int* in_sizes, int n_in,
                              void* d_out, int out_size, void* d_ws, size_t ws_size,
                              hipStream_t stream) {
    const float* x      = (const float*)d_in[0];
    const float* norm_w = (const float*)d_in[1];
    const float* norm_b = (const float*)d_in[2];
    const float* qkv_w  = (const float*)d_in[3];
    const float* qkv_b  = (const float*)d_in[4];
    const float* out_w  = (const float*)d_in[5];
    const float* out_b  = (const float*)d_in[6];
    const float* onw    = (const float*)d_in[7];
    const float* onb    = (const float*)d_in[8];
    float* out = (float*)d_out;

    char* w = (char*)d_ws;
    size_t off = 0;
    auto al = [&](size_t n) { size_t o = off; off += (n + 255) & ~(size_t)255; return o; };
    const size_t bufsz = (size_t)NB * NC * NSP * 2;          // 33.5 MB each
    unsigned short* qbuf = (unsigned short*)(w + al(bufsz));
    unsigned short* kbuf = (unsigned short*)(w + al(bufsz));
    unsigned short* vbuf = (unsigned short*)(w + al(bufsz));
    unsigned short* ybuf = (unsigned short*)(w + al(bufsz));
    unsigned short* w16  = (unsigned short*)(w + al((size_t)O3 * NC * 2));
    unsigned short* ow16 = (unsigned short*)(w + al((size_t)NC * NC * 2));
    float* gn1part = (float*)(w + al((size_t)NB * NC * 2 * 4));
    float* gn1stat = (float*)(w + al((size_t)NB * NG * 2 * 4));
    float* gn2part = (float*)(w + al((size_t)NB * NC * 2 * 4));
    float* gn2stat = (float*)(w + al((size_t)NB * NG * 2 * 4));
    float* qsbuf   = (float*)(w + al((size_t)NB * NH * NSP * 4));          // 2 MB
    float* KV2f    = (float*)(w + al((size_t)NB * NH * HDIM * HDIM * 4));  // 64 KB
    unsigned short* Mf = (unsigned short*)(w + al((size_t)NB * NC * NC * 2)); // 256 KB
    // KVpart/Spart alias ybuf: fully consumed by k_kvfin before k_out writes ybuf.
    float* KVpart = (float*)ybuf;                                        // 16*NCH*1024*4 = 4 MB
    float* Spart  = (float*)(ybuf + (size_t)NB * NH * NCH * 1024 * 2);   // after KVpart

    (void)hipMemsetAsync(gn2part, 0, (size_t)NB * NC * 2 * sizeof(float), stream);

    k_convw<<<dim3(256), dim3(256), 0, stream>>>(qkv_w, out_w, w16, ow16);
    k_stat_f32<<<dim3(NB * NC), dim3(256), 0, stream>>>(x, gn1part);
    k_gnfin<<<dim3(1), dim3(64), 0, stream>>>(gn1part, gn1stat);
    k_qkv<<<dim3(NSP / 64, NB), dim3(256), 0, stream>>>(x, norm_w, norm_b, w16, qkv_b, gn1stat,
                                                        qbuf, kbuf, vbuf, qsbuf);
    k_kv<<<dim3(NCH, NH, NB), dim3(256), 0, stream>>>(kbuf, vbuf, KVpart, Spart);
    k_kvfin<<<dim3(NB * NH), dim3(256), 0, stream>>>(KVpart, Spart, KV2f);
    k_fold<<<dim3(NH, NB), dim3(256), 0, stream>>>(ow16, KV2f, Mf);
    k_out<<<dim3(NSP / 64, NB), dim3(256), 0, stream>>>(qbuf, qsbuf, Mf, out_b, ybuf, gn2part);
    k_gnfin<<<dim3(1), dim3(64), 0, stream>>>(gn2part, gn2stat);
    k_final<<<dim3((NB * NC * NSP) / (256 * 8)), dim3(256), 0, stream>>>(x, ybuf, onw, onb, gn2stat, out);
}

// Round 6
// 463.144 us; speedup vs baseline: 1.0110x; 1.0110x over previous
//
#include <hip/hip_runtime.h>
#include <hip/hip_bf16.h>
#include <cstdint>

#define NB   2
#define NC   256
#define NSP  32768     // D*H*W
#define NG   32
#define CPG  8         // NC/NG
#define NH   8
#define HDIM 32
#define O3   768
#define NCH  64        // k_kv spatial chunks
#define GN_EPS 1e-5f

typedef __attribute__((ext_vector_type(4))) float f32x4;
typedef __attribute__((ext_vector_type(8))) short short8;
typedef __attribute__((ext_vector_type(4))) short s16x4;

static __device__ __forceinline__ float bf2f(unsigned short u) {
    union { unsigned int i; float f; } v; v.i = ((unsigned int)u) << 16; return v.f;
}
static __device__ __forceinline__ unsigned short f2bf(float f) {
    union { float f; unsigned int i; } v; v.f = f;
    unsigned int lsb = (v.i >> 16) & 1u;
    return (unsigned short)((v.i + 0x7fffu + lsb) >> 16);
}
static __device__ __forceinline__ float elu1(float x) {
    return x > 0.f ? x + 1.f : __expf(x);
}

// ---------------- weight fp32 -> bf16 ----------------
__global__ __launch_bounds__(256) void k_convw(const float* __restrict__ qkvw,
                                               const float* __restrict__ outw,
                                               unsigned short* __restrict__ w16,
                                               unsigned short* __restrict__ ow16) {
    int i = blockIdx.x * 256 + threadIdx.x;
    for (int idx = i; idx < O3 * NC; idx += gridDim.x * 256) w16[idx] = f2bf(qkvw[idx]);
    for (int idx = i; idx < NC * NC; idx += gridDim.x * 256) ow16[idx] = f2bf(outw[idx]);
}

// ---------------- per-(b,c) sum/sumsq, fp32 input ----------------
__global__ __launch_bounds__(256) void k_stat_f32(const float* __restrict__ x, float* __restrict__ part) {
    int bc = blockIdx.x;
    const float* p = x + (size_t)bc * NSP;
    int t = threadIdx.x;
    float s = 0.f, s2 = 0.f;
    for (int i = t * 4; i < NSP; i += 256 * 4) {
        float4 v = *reinterpret_cast<const float4*>(p + i);
        s  += v.x + v.y + v.z + v.w;
        s2 += v.x * v.x + v.y * v.y + v.z * v.z + v.w * v.w;
    }
    #pragma unroll
    for (int o = 32; o > 0; o >>= 1) { s += __shfl_down(s, o, 64); s2 += __shfl_down(s2, o, 64); }
    __shared__ float red[8];
    if ((t & 63) == 0) { red[(t >> 6) * 2] = s; red[(t >> 6) * 2 + 1] = s2; }
    __syncthreads();
    if (t == 0) {
        part[bc * 2]     = red[0] + red[2] + red[4] + red[6];
        part[bc * 2 + 1] = red[1] + red[3] + red[5] + red[7];
    }
}

// ---------------- finalize group stats: per (b,g) mu, rsig ----------------
__global__ __launch_bounds__(64) void k_gnfin(const float* __restrict__ part, float* __restrict__ stat) {
    int i = threadIdx.x;
    if (i < NB * NG) {
        int b = i / NG, g = i % NG;
        float s = 0.f, s2 = 0.f;
        #pragma unroll
        for (int cc = 0; cc < CPG; ++cc) {
            int bc = b * NC + g * CPG + cc;
            s += part[bc * 2]; s2 += part[bc * 2 + 1];
        }
        float cnt = (float)(CPG * NSP);
        float mu = s / cnt;
        float var = s2 / cnt - mu * mu;
        stat[i * 2] = mu;
        stat[i * 2 + 1] = rsqrtf(var + GN_EPS);
    }
}

// ---------------- fused gn1-apply + qkv GEMM + bias + elu + q-normalize, store q'(transposed)/k/v ----------
// grid (NSP/64, NB), 256 threads (4 waves). W register-pipelined from L2; no K-loop barriers.
// q' = elu(q)/qsum stored TRANSPOSED as q2[b][n][c] so k_out staging is coalesced row copies.
__global__ __launch_bounds__(256, 3) void k_qkv(const float* __restrict__ x,
                                             const float* __restrict__ nw, const float* __restrict__ nb,
                                             const unsigned short* __restrict__ w16,
                                             const float* __restrict__ qkvb,
                                             const float* __restrict__ gn1,
                                             unsigned short* __restrict__ q2,
                                             unsigned short* __restrict__ kb,
                                             unsigned short* __restrict__ vb) {
    __shared__ unsigned short Ht[64][264];   // h transposed [n][c]
    int b = blockIdx.y;
    int n0 = blockIdx.x * 64;
    int t = threadIdx.x;

    {   // stage h = (x-mu)*rsig*nw + nb, transposed, bf16 (r2-proven float4 pattern)
        int j = t & 15, cr = t >> 4;
        #pragma unroll
        for (int it = 0; it < 16; ++it) {
            int c = it * 16 + cr;
            float4 v = *reinterpret_cast<const float4*>(x + ((size_t)(b * NC + c)) * NSP + n0 + j * 4);
            int g = c >> 3;
            float mu = gn1[(b * NG + g) * 2], rs = gn1[(b * NG + g) * 2 + 1];
            float sc = rs * nw[c];
            float bi = nb[c] - mu * sc;
            Ht[j * 4 + 0][c] = f2bf(v.x * sc + bi);
            Ht[j * 4 + 1][c] = f2bf(v.y * sc + bi);
            Ht[j * 4 + 2][c] = f2bf(v.z * sc + bi);
            Ht[j * 4 + 3][c] = f2bf(v.w * sc + bi);
        }
    }
    __syncthreads();

    int w = t >> 6, l = t & 63, mr = l & 15, kg = l >> 4;
    for (int mp = 0; mp < 3; ++mp) {
        const unsigned short* arow[4];
        #pragma unroll
        for (int mt = 0; mt < 4; ++mt)
            arow[mt] = w16 + (size_t)(mp * 256 + w * 64 + mt * 16 + mr) * NC + kg * 8;
        f32x4 acc[4][4];
        #pragma unroll
        for (int a = 0; a < 4; ++a)
            #pragma unroll
            for (int n2 = 0; n2 < 4; ++n2) acc[a][n2] = (f32x4){0.f, 0.f, 0.f, 0.f};
        short8 afc[4], afn[4];
        #pragma unroll
        for (int mt = 0; mt < 4; ++mt) afc[mt] = *reinterpret_cast<const short8*>(arow[mt]);
        #pragma unroll 2
        for (int kc = 0; kc < 8; ++kc) {
            if (kc < 7) {
                #pragma unroll
                for (int mt = 0; mt < 4; ++mt)
                    afn[mt] = *reinterpret_cast<const short8*>(arow[mt] + (kc + 1) * 32);
            }
            int k0 = kc * 32 + kg * 8;
            short8 bfr[4];
            #pragma unroll
            for (int nt = 0; nt < 4; ++nt)
                bfr[nt] = *reinterpret_cast<const short8*>(&Ht[nt * 16 + mr][k0]);
            #pragma unroll
            for (int mt = 0; mt < 4; ++mt)
                #pragma unroll
                for (int nt = 0; nt < 4; ++nt)
                    acc[mt][nt] = __builtin_amdgcn_mfma_f32_16x16x32_bf16(afc[mt], bfr[nt], acc[mt][nt], 0, 0, 0);
            #pragma unroll
            for (int mt = 0; mt < 4; ++mt) afc[mt] = afn[mt];
        }
        if (mp == 0) {
            // q: elu, per-head qsum (heads 2w: mt 0-1, 2w+1: mt 2-3), divide, store transposed [n][c]
            #pragma unroll
            for (int nt = 0; nt < 4; ++nt) {
                int n = n0 + nt * 16 + mr;
                float vals[16];
                float sh0 = 0.f, sh1 = 0.f;
                #pragma unroll
                for (int mt = 0; mt < 4; ++mt)
                    #pragma unroll
                    for (int r = 0; r < 4; ++r) {
                        float val = elu1(acc[mt][nt][r] + qkvb[w * 64 + mt * 16 + kg * 4 + r]);
                        vals[mt * 4 + r] = val;
                        if (mt < 2) sh0 += val; else sh1 += val;
                    }
                sh0 += __shfl_xor(sh0, 16, 64); sh0 += __shfl_xor(sh0, 32, 64);
                sh1 += __shfl_xor(sh1, 16, 64); sh1 += __shfl_xor(sh1, 32, 64);
                float inv0 = 1.0f / fmaxf(sh0, 1e-6f);
                float inv1 = 1.0f / fmaxf(sh1, 1e-6f);
                unsigned short* qrow = q2 + ((size_t)b * NSP + n) * NC;
                #pragma unroll
                for (int mt = 0; mt < 4; ++mt) {
                    float inv = (mt < 2) ? inv0 : inv1;
                    s16x4 pk;
                    #pragma unroll
                    for (int r = 0; r < 4; ++r) pk[r] = (short)f2bf(vals[mt * 4 + r] * inv);
                    *reinterpret_cast<s16x4*>(qrow + w * 64 + mt * 16 + kg * 4) = pk;
                }
            }
        } else {
            unsigned short* dst = (mp == 1) ? kb : vb;
            #pragma unroll
            for (int mt = 0; mt < 4; ++mt) {
                #pragma unroll
                for (int nt = 0; nt < 4; ++nt) {
                    int n = n0 + nt * 16 + mr;
                    #pragma unroll
                    for (int r = 0; r < 4; ++r) {
                        int olocal = w * 64 + mt * 16 + kg * 4 + r;
                        float val = acc[mt][nt][r] + qkvb[mp * 256 + olocal];
                        if (mp == 1) val = elu1(val);
                        dst[((size_t)(b * NC + olocal)) * NSP + n] = f2bf(val);
                    }
                }
            }
        }
    }
}

// ---------------- KV partials via MFMA: KV[d][e] = sum_n k[d][n] v[e][n] ----------------
// grid (NCH, NH, NB), 256 threads (4 waves). Per block: 512 n, per wave 128 n.
__global__ __launch_bounds__(256) void k_kv(const unsigned short* __restrict__ kb,
                                            const unsigned short* __restrict__ vb,
                                            float* __restrict__ KVpart, float* __restrict__ Spart) {
    int ch = blockIdx.x, h = blockIdx.y, b = blockIdx.z;
    int t = threadIdx.x, w = t >> 6, l = t & 63;
    int d16 = l & 15, kg = l >> 4;
    size_t base = ((size_t)(b * NC + h * HDIM)) * NSP + ch * 512 + w * 128;
    const unsigned short* kp = kb + base;
    const unsigned short* vp = vb + base;

    f32x4 acc[2][2];
    #pragma unroll
    for (int a = 0; a < 2; ++a)
        #pragma unroll
        for (int c = 0; c < 2; ++c) acc[a][c] = (f32x4){0.f, 0.f, 0.f, 0.f};
    float s0 = 0.f, s1 = 0.f;
    #pragma unroll
    for (int step = 0; step < 4; ++step) {
        int nof = step * 32 + kg * 8;
        short8 ak0 = *reinterpret_cast<const short8*>(kp + (size_t)(d16) * NSP + nof);
        short8 ak1 = *reinterpret_cast<const short8*>(kp + (size_t)(16 + d16) * NSP + nof);
        short8 av0 = *reinterpret_cast<const short8*>(vp + (size_t)(d16) * NSP + nof);
        short8 av1 = *reinterpret_cast<const short8*>(vp + (size_t)(16 + d16) * NSP + nof);
        acc[0][0] = __builtin_amdgcn_mfma_f32_16x16x32_bf16(ak0, av0, acc[0][0], 0, 0, 0);
        acc[0][1] = __builtin_amdgcn_mfma_f32_16x16x32_bf16(ak0, av1, acc[0][1], 0, 0, 0);
        acc[1][0] = __builtin_amdgcn_mfma_f32_16x16x32_bf16(ak1, av0, acc[1][0], 0, 0, 0);
        acc[1][1] = __builtin_amdgcn_mfma_f32_16x16x32_bf16(ak1, av1, acc[1][1], 0, 0, 0);
        #pragma unroll
        for (int j = 0; j < 8; ++j) { s0 += bf2f((unsigned short)ak0[j]); s1 += bf2f((unsigned short)ak1[j]); }
    }
    s0 += __shfl_down(s0, 32, 64); s0 += __shfl_down(s0, 16, 64);
    s1 += __shfl_down(s1, 32, 64); s1 += __shfl_down(s1, 16, 64);

    __shared__ float red[4][1024];
    __shared__ float sred[4][32];
    #pragma unroll
    for (int et = 0; et < 2; ++et)
        #pragma unroll
        for (int nt = 0; nt < 2; ++nt)
            #pragma unroll
            for (int r = 0; r < 4; ++r) {
                int d = et * 16 + kg * 4 + r;
                int e = nt * 16 + d16;
                red[w][d * 32 + e] = acc[et][nt][r];
            }
    if (l < 16) { sred[w][l] = s0; sred[w][16 + l] = s1; }
    __syncthreads();
    int bh = b * NH + h;
    float* kvout = KVpart + ((size_t)bh * NCH + ch) * 1024;
    for (int i = t; i < 1024; i += 256) kvout[i] = red[0][i] + red[1][i] + red[2][i] + red[3][i];
    if (t < 32) Spart[(bh * NCH + ch) * 32 + t] = sred[0][t] + sred[1][t] + sred[2][t] + sred[3][t];
}

// ---------------- reduce partials: KV2f[d][e] = KV[d][e]/max(S[d],1e-6), fp32 ----------------
__global__ __launch_bounds__(256) void k_kvfin(const float* __restrict__ KVpart, const float* __restrict__ Spart,
                                               float* __restrict__ KV2f) {
    int bh = blockIdx.x, t = threadIdx.x;
    __shared__ float Sl[32];
    if (t < 32) {
        float s = 0.f;
        for (int ch = 0; ch < NCH; ++ch) s += Spart[(bh * NCH + ch) * 32 + t];
        Sl[t] = fmaxf(s, 1e-6f);
    }
    __syncthreads();
    for (int i = t; i < 1024; i += 256) {
        float s = 0.f;
        #pragma unroll 8
        for (int ch = 0; ch < NCH; ++ch) s += KVpart[((size_t)bh * NCH + ch) * 1024 + i];
        KV2f[bh * 1024 + i] = s / Sl[i >> 5];
    }
}

// ---------------- fold: Mf[b][o][h*32+d] = sum_e ow[o][h*32+e] * KV2f[b][h][d][e] ----------------
// grid (NH, NB), 256 threads (thread = o).
__global__ __launch_bounds__(256) void k_fold(const unsigned short* __restrict__ ow16,
                                              const float* __restrict__ KV2f,
                                              unsigned short* __restrict__ Mf) {
    int h = blockIdx.x, b = blockIdx.y, t = threadIdx.x;
    __shared__ float kv[HDIM][HDIM];
    for (int i = t; i < HDIM * HDIM; i += 256) kv[i >> 5][i & 31] = KV2f[(b * NH + h) * 1024 + i];
    __syncthreads();
    int o = t;
    float owv[32];
    #pragma unroll
    for (int e = 0; e < 32; ++e) owv[e] = bf2f(ow16[o * NC + h * 32 + e]);
    #pragma unroll
    for (int dq = 0; dq < 4; ++dq) {
        short8 pk;
        #pragma unroll
        for (int dr = 0; dr < 8; ++dr) {
            int d = dq * 8 + dr;
            float s = 0.f;
            #pragma unroll
            for (int e = 0; e < 32; ++e) s += owv[e] * kv[d][e];
            pk[dr] = (short)f2bf(s);
        }
        *reinterpret_cast<short8*>(Mf + ((size_t)b * NC + o) * NC + h * 32 + dq * 8) = pk;
    }
}

// ---------------- out GEMM: y[o][n] = sum_c Mf[o][c] * q'[n][c] + outb[o], fused gn2 stats ----------
// grid (NSP/64, NB), 256 threads (4 waves). q' staged via coalesced row copies (16B/lane).
__global__ __launch_bounds__(256, 3) void k_out(const unsigned short* __restrict__ q2,
                                             const unsigned short* __restrict__ Mf,
                                             const float* __restrict__ outb,
                                             unsigned short* __restrict__ yb,
                                             float* __restrict__ gn2part) {
    __shared__ unsigned short qT[64][264];
    int b = blockIdx.y, n0 = blockIdx.x * 64, t = threadIdx.x;

    {   // stage q' rows: fully coalesced 16B loads, linear 16B ds_writes
        int rn = t >> 5, co = t & 31;
        const unsigned short* qsrc = q2 + ((size_t)b * NSP + n0) * NC;
        #pragma unroll
        for (int pass = 0; pass < 8; ++pass) {
            int n = pass * 8 + rn;
            short8 v = *reinterpret_cast<const short8*>(qsrc + (size_t)n * NC + co * 8);
            *reinterpret_cast<short8*>(&qT[n][co * 8]) = v;
        }
    }
    __syncthreads();

    int w = t >> 6, l = t & 63, mr = l & 15, kg = l >> 4;
    const unsigned short* arow[4];
    #pragma unroll
    for (int mt = 0; mt < 4; ++mt)
        arow[mt] = Mf + (size_t)b * NC * NC + (size_t)(w * 64 + mt * 16 + mr) * NC + kg * 8;
    f32x4 acc[4][4];
    #pragma unroll
    for (int a = 0; a < 4; ++a)
        #pragma unroll
        for (int n2 = 0; n2 < 4; ++n2) acc[a][n2] = (f32x4){0.f, 0.f, 0.f, 0.f};
    short8 afc[4], afn[4];
    #pragma unroll
    for (int mt = 0; mt < 4; ++mt) afc[mt] = *reinterpret_cast<const short8*>(arow[mt]);
    #pragma unroll 2
    for (int kc = 0; kc < 8; ++kc) {
        if (kc < 7) {
            #pragma unroll
            for (int mt = 0; mt < 4; ++mt)
                afn[mt] = *reinterpret_cast<const short8*>(arow[mt] + (kc + 1) * 32);
        }
        int k0 = kc * 32 + kg * 8;
        short8 bfr[4];
        #pragma unroll
        for (int nt = 0; nt < 4; ++nt)
            bfr[nt] = *reinterpret_cast<const short8*>(&qT[nt * 16 + mr][k0]);
        #pragma unroll
        for (int mt = 0; mt < 4; ++mt)
            #pragma unroll
            for (int nt = 0; nt < 4; ++nt)
                acc[mt][nt] = __builtin_amdgcn_mfma_f32_16x16x32_bf16(afc[mt], bfr[nt], acc[mt][nt], 0, 0, 0);
        #pragma unroll
        for (int mt = 0; mt < 4; ++mt) afc[mt] = afn[mt];
    }
    // epilogue: store y, accumulate gn2 stats (sum, sumsq) per channel
    float s1[16], s2[16];
    #pragma unroll
    for (int i = 0; i < 16; ++i) { s1[i] = 0.f; s2[i] = 0.f; }
    #pragma unroll
    for (int mt = 0; mt < 4; ++mt) {
        #pragma unroll
        for (int nt = 0; nt < 4; ++nt) {
            int n = n0 + nt * 16 + mr;
            #pragma unroll
            for (int r = 0; r < 4; ++r) {
                int o = w * 64 + mt * 16 + kg * 4 + r;
                float val = acc[mt][nt][r] + outb[o];
                yb[((size_t)(b * NC + o)) * NSP + n] = f2bf(val);
                s1[mt * 4 + r] += val;
                s2[mt * 4 + r] += val * val;
            }
        }
    }
    #pragma unroll
    for (int i = 0; i < 16; ++i) {
        float a = s1[i], q2v = s2[i];
        a += __shfl_down(a, 8, 64);  q2v += __shfl_down(q2v, 8, 64);
        a += __shfl_down(a, 4, 64);  q2v += __shfl_down(q2v, 4, 64);
        a += __shfl_down(a, 2, 64);  q2v += __shfl_down(q2v, 2, 64);
        a += __shfl_down(a, 1, 64);  q2v += __shfl_down(q2v, 1, 64);
        if (mr == 0) {
            int o = w * 64 + (i >> 2) * 16 + kg * 4 + (i & 3);
            atomicAdd(&gn2part[(b * NC + o) * 2], a);
            atomicAdd(&gn2part[(b * NC + o) * 2 + 1], q2v);
        }
    }
}

// ---------------- final: out = x + gn2(y) ----------------
__global__ __launch_bounds__(256) void k_final(const float* __restrict__ x,
                                               const unsigned short* __restrict__ yb,
                                               const float* __restrict__ onw, const float* __restrict__ onb,
                                               const float* __restrict__ gn2, float* __restrict__ out) {
    size_t base = ((size_t)blockIdx.x * 256 + threadIdx.x) * 8;
    int bc = (int)(base >> 15);           // b*NC + c
    int c = bc & (NC - 1);
    int b = bc >> 8;
    int g = c >> 3;
    float mu = gn2[(b * NG + g) * 2], rs = gn2[(b * NG + g) * 2 + 1];
    float sc = rs * onw[c], bi = onb[c] - mu * sc;
    short8 v = *reinterpret_cast<const short8*>(yb + base);
    float4 x0 = *reinterpret_cast<const float4*>(x + base);
    float4 x1 = *reinterpret_cast<const float4*>(x + base + 4);
    float4 o0, o1;
    o0.x = x0.x + bf2f((unsigned short)v[0]) * sc + bi;
    o0.y = x0.y + bf2f((unsigned short)v[1]) * sc + bi;
    o0.z = x0.z + bf2f((unsigned short)v[2]) * sc + bi;
    o0.w = x0.w + bf2f((unsigned short)v[3]) * sc + bi;
    o1.x = x1.x + bf2f((unsigned short)v[4]) * sc + bi;
    o1.y = x1.y + bf2f((unsigned short)v[5]) * sc + bi;
    o1.z = x1.z + bf2f((unsigned short)v[6]) * sc + bi;
    o1.w = x1.w + bf2f((unsigned short)v[7]) * sc + bi;
    *reinterpret_cast<float4*>(out + base) = o0;
    *reinterpret_cast<float4*>(out + base + 4) = o1;
}

extern "C" void kernel_launch(void* const* d_in, const int* in_sizes, int n_in,
                              void* d_out, int out_size, void* d_ws, size_t ws_size,
                              hipStream_t stream) {
    const float* x      = (const float*)d_in[0];
    const float* norm_w = (const float*)d_in[1];
    const float* norm_b = (const float*)d_in[2];
    const float* qkv_w  = (const float*)d_in[3];
    const float* qkv_b  = (const float*)d_in[4];
    const float* out_w  = (const float*)d_in[5];
    const float* out_b  = (const float*)d_in[6];
    const float* onw    = (const float*)d_in[7];
    const float* onb    = (const float*)d_in[8];
    float* out = (float*)d_out;

    char* w = (char*)d_ws;
    size_t off = 0;
    auto al = [&](size_t n) { size_t o = off; off += (n + 255) & ~(size_t)255; return o; };
    const size_t bufsz = (size_t)NB * NC * NSP * 2;          // 33.5 MB each
    unsigned short* q2buf = (unsigned short*)(w + al(bufsz));   // q' transposed [b][n][c]
    unsigned short* kbuf  = (unsigned short*)(w + al(bufsz));
    unsigned short* vbuf  = (unsigned short*)(w + al(bufsz));
    unsigned short* ybuf  = (unsigned short*)(w + al(bufsz));
    unsigned short* w16   = (unsigned short*)(w + al((size_t)O3 * NC * 2));
    unsigned short* ow16  = (unsigned short*)(w + al((size_t)NC * NC * 2));
    float* gn1part = (float*)(w + al((size_t)NB * NC * 2 * 4));
    float* gn1stat = (float*)(w + al((size_t)NB * NG * 2 * 4));
    float* gn2part = (float*)(w + al((size_t)NB * NC * 2 * 4));
    float* gn2stat = (float*)(w + al((size_t)NB * NG * 2 * 4));
    float* KV2f    = (float*)(w + al((size_t)NB * NH * HDIM * HDIM * 4));  // 64 KB
    unsigned short* Mf = (unsigned short*)(w + al((size_t)NB * NC * NC * 2)); // 256 KB
    // KVpart/Spart alias ybuf: fully consumed by k_kvfin before k_out writes ybuf.
    float* KVpart = (float*)ybuf;                                        // 16*NCH*1024*4 = 4 MB
    float* Spart  = (float*)(ybuf + (size_t)NB * NH * NCH * 1024 * 2);   // after KVpart

    (void)hipMemsetAsync(gn2part, 0, (size_t)NB * NC * 2 * sizeof(float), stream);

    k_convw<<<dim3(256), dim3(256), 0, stream>>>(qkv_w, out_w, w16, ow16);
    k_stat_f32<<<dim3(NB * NC), dim3(256), 0, stream>>>(x, gn1part);
    k_gnfin<<<dim3(1), dim3(64), 0, stream>>>(gn1part, gn1stat);
    k_qkv<<<dim3(NSP / 64, NB), dim3(256), 0, stream>>>(x, norm_w, norm_b, w16, qkv_b, gn1stat,
                                                        q2buf, kbuf, vbuf);
    k_kv<<<dim3(NCH, NH, NB), dim3(256), 0, stream>>>(kbuf, vbuf, KVpart, Spart);
    k_kvfin<<<dim3(NB * NH), dim3(256), 0, stream>>>(KVpart, Spart, KV2f);
    k_fold<<<dim3(NH, NB), dim3(256), 0, stream>>>(ow16, KV2f, Mf);
    k_out<<<dim3(NSP / 64, NB), dim3(256), 0, stream>>>(q2buf, Mf, out_b, ybuf, gn2part);
    k_gnfin<<<dim3(1), dim3(64), 0, stream>>>(gn2part, gn2stat);
    k_final<<<dim3((NB * NC * NSP) / (256 * 8)), dim3(256), 0, stream>>>(x, ybuf, onw, onb, gn2stat, out);
}